// Round 15
// baseline (161.749 us; speedup 1.0000x reference)
//
#include <hip/hip_runtime.h>

#define N_NODES 100000
#define NUM_TYPES 8
#define FACTOR 0.125f      // 1/sqrt(64)

#define S_CHUNK 25600      // nodes per chunk; bins 100 KB + full tt4 50 KB = 153.9 KB LDS
#define C_CHUNKS 4         // 4*25600 = 102400 >= 100000
#define THR 1024
#define B_TARGET 64        // grid = 4*64 = 256 blocks (1/CU)
#define NXCD 8             // blockIdx % 8 ~ XCD under round-robin dispatch

// ---------- Kernel 0: pack atom_type into nibble table (50 KB) ----------
__global__ __launch_bounds__(256) void type_pack_kernel(
    const int* __restrict__ atom_type, unsigned char* __restrict__ tt4, int N)
{
    int i = blockIdx.x * blockDim.x + threadIdx.x;   // nibble-pair index
    if (i >= C_CHUNKS * S_CHUNK / 2) return;
    int n0 = 2 * i, n1 = 2 * i + 1;
    unsigned char t0 = (n0 < N) ? (unsigned char)atom_type[n0] : 0;
    unsigned char t1 = (n1 < N) ? (unsigned char)atom_type[n1] : 0;
    tt4[i] = (unsigned char)(t0 | (t1 << 4));
}

// ---------- Kernel 1: fused chunk-sum, all-LDS lookups, x4 unrolled ----------
// Ladder: r10 1.73 cyc/edge-visit (global u8 gather) -> r12 1.39 (all-LDS
// lookups) -> r13 1.27 (x2 unroll; lean-loop floor is 1.24). Stall source:
// 3-deep LDS chain (nibble -> scale -> ds_add) at only 4 waves/SIMD (154 KB
// LDS = 1 block/CU). x4 unroll: 16 independent edge chains/thread, zero LDS
// cost, VGPR ~52->~76 (LDS is the occupancy binder, so free).
// Mapping (r10, -4x FETCH): x=blk&7, o=blk>>3, c=o&3, b=x*(B/8)+(o>>2) keeps
// a segment's 4 chunk-blocks on one XCD -> edge lines fetched once per XCD.
__global__ __launch_bounds__(THR) void fused_chunk_sum_kernel(
    const int* __restrict__ centers,
    const int* __restrict__ neighbors,
    const float* __restrict__ eng,
    const unsigned char* __restrict__ tt4,  // [C*S/2] nibble-packed types (padded)
    const float* __restrict__ scales,
    float* __restrict__ partials,           // [C_CHUNKS][B][S_CHUNK]
    int E, int B)
{
    __shared__ __align__(16) float bins[S_CHUNK];
    __shared__ __align__(16) unsigned char s_tt4[C_CHUNKS * S_CHUNK / 2];  // 50 KB
    __shared__ float s_scales[NUM_TYPES * NUM_TYPES];

    const int x = blockIdx.x & (NXCD - 1);   // XCD id (round-robin dispatch)
    const int o = blockIdx.x >> 3;           // ordinal within XCD
    const int c = o & 3;                     // chunk
    const int b = x * (B >> 3) + (o >> 2);   // edge segment (B % 8 == 0)
    const int base = c * S_CHUNK;

    if (threadIdx.x < NUM_TYPES * NUM_TYPES)
        s_scales[threadIdx.x] = scales[threadIdx.x] * FACTOR;   // fold FACTOR

    float4* bins4 = (float4*)bins;
    for (int j = threadIdx.x; j < S_CHUNK / 4; j += THR)
        bins4[j] = make_float4(0.f, 0.f, 0.f, 0.f);
    {   // stage full nibble table: 51 200 B = 3200 uint4
        const uint4* src = (const uint4*)tt4;
        uint4* dst = (uint4*)s_tt4;
        for (int j = threadIdx.x; j < C_CHUNKS * S_CHUNK / 2 / 16; j += THR)
            dst[j] = src[j];
    }
    __syncthreads();

    const int n4 = E >> 2;

// type of global node index G from the LDS nibble table
#define TY(G)  (int)((s_tt4[(unsigned)(G) >> 1] >> (((unsigned)(G) & 1u) << 2)) & 7u)
#define BODY(CC, NN, EE) { \
        unsigned j0 = (unsigned)((CC).x - base); \
        unsigned j1 = (unsigned)((CC).y - base); \
        unsigned j2 = (unsigned)((CC).z - base); \
        unsigned j3 = (unsigned)((CC).w - base); \
        if (j0 < S_CHUNK) atomicAdd(&bins[j0], (EE).x * s_scales[TY((CC).x) * NUM_TYPES + TY((NN).x)]); \
        if (j1 < S_CHUNK) atomicAdd(&bins[j1], (EE).y * s_scales[TY((CC).y) * NUM_TYPES + TY((NN).y)]); \
        if (j2 < S_CHUNK) atomicAdd(&bins[j2], (EE).z * s_scales[TY((CC).z) * NUM_TYPES + TY((NN).z)]); \
        if (j3 < S_CHUNK) atomicAdd(&bins[j3], (EE).w * s_scales[TY((CC).w) * NUM_TYPES + TY((NN).w)]); }

    // x4-unrolled sweep: block-tile of 4*THR quads per stride; all four quads'
    // loads hoisted -> 16 independent edge chains in flight per thread.
    for (int i = b * (4 * THR) + (int)threadIdx.x; i < n4; i += B * (4 * THR)) {
        const int i1 = i + THR, i2 = i + 2 * THR, i3 = i + 3 * THR;
        const bool h1 = (i1 < n4), h2 = (i2 < n4), h3 = (i3 < n4);

        int4   cc0 = ((const int4*)centers)[i];
        int4   nn0 = ((const int4*)neighbors)[i];
        float4 e0  = ((const float4*)eng)[i];
        int4 cc1, nn1, cc2, nn2, cc3, nn3;
        float4 e1, e2, e3;
        if (h1) { cc1 = ((const int4*)centers)[i1]; nn1 = ((const int4*)neighbors)[i1]; e1 = ((const float4*)eng)[i1]; }
        if (h2) { cc2 = ((const int4*)centers)[i2]; nn2 = ((const int4*)neighbors)[i2]; e2 = ((const float4*)eng)[i2]; }
        if (h3) { cc3 = ((const int4*)centers)[i3]; nn3 = ((const int4*)neighbors)[i3]; e3 = ((const float4*)eng)[i3]; }

        BODY(cc0, nn0, e0)
        if (h1) BODY(cc1, nn1, e1)
        if (h2) BODY(cc2, nn2, e2)
        if (h3) BODY(cc3, nn3, e3)
    }

    // tail (E % 4) — dead for E = 6,400,000; b==0 occurs once per chunk
    // (x=0, o=0..3 -> c=0..3, b=0)
    if (b == 0) {
        for (int i = (n4 << 2) + (int)threadIdx.x; i < E; i += THR) {
            int cn = centers[i];
            unsigned j = (unsigned)(cn - base);
            if (j < S_CHUNK)
                atomicAdd(&bins[j], eng[i] * s_scales[TY(cn) * NUM_TYPES + TY(neighbors[i])]);
        }
    }
#undef BODY
#undef TY

    __syncthreads();
    float4* dst4 = (float4*)(partials + ((size_t)c * B + b) * S_CHUNK);
    for (int j = threadIdx.x; j < S_CHUNK / 4; j += THR) dst4[j] = bins4[j];
}

// ---------- Kernel 2: reduce segment partials (float4) ----------
__global__ __launch_bounds__(256) void reduce_kernel(
    const float* __restrict__ partials, float* __restrict__ out, int B, int N4)
{
    int t = blockIdx.x * blockDim.x + threadIdx.x;
    if (t >= N4) return;
    int n = t * 4;
    int c = n / S_CHUNK;
    int j = n - c * S_CHUNK;
    const float4* p = (const float4*)(partials + ((size_t)c * B) * S_CHUNK + j);
    float4 s = make_float4(0.f, 0.f, 0.f, 0.f);
    for (int b = 0; b < B; ++b) {
        float4 v = p[(size_t)b * (S_CHUNK / 4)];
        s.x += v.x; s.y += v.y; s.z += v.z; s.w += v.w;
    }
    ((float4*)out)[t] = s;
}

__global__ __launch_bounds__(256) void reduce_scalar_kernel(
    const float* __restrict__ partials, float* __restrict__ out, int B, int N)
{
    int n = blockIdx.x * blockDim.x + threadIdx.x;
    if (n >= N) return;
    int c = n / S_CHUNK;
    int j = n - c * S_CHUNK;
    const float* p = partials + ((size_t)c * B) * S_CHUNK + j;
    float s = 0.0f;
    for (int b = 0; b < B; ++b) s += p[(size_t)b * S_CHUNK];
    out[n] = s;
}

// ---------- Fallback (tiny workspace only): direct atomic scatter ----------
__global__ __launch_bounds__(256) void edge_sum_atomic_kernel(
    const int* __restrict__ centers, const int* __restrict__ neighbors,
    const float* __restrict__ eng, const int* __restrict__ atom_type,
    const float* __restrict__ scales, float* __restrict__ out, int E)
{
    __shared__ float s_scales[NUM_TYPES * NUM_TYPES];
    if (threadIdx.x < NUM_TYPES * NUM_TYPES) s_scales[threadIdx.x] = scales[threadIdx.x];
    __syncthreads();
    int tid = blockIdx.x * blockDim.x + threadIdx.x;
    int stride = gridDim.x * blockDim.x;
    for (int i = tid; i < E; i += stride) {
        int cn = centers[i];
        float v = eng[i] * s_scales[atom_type[cn] * NUM_TYPES + atom_type[neighbors[i]]] * FACTOR;
        unsafeAtomicAdd(&out[cn], v);
    }
}

extern "C" void kernel_launch(void* const* d_in, const int* in_sizes, int n_in,
                              void* d_out, int out_size, void* d_ws, size_t ws_size,
                              hipStream_t stream) {
    const int E = in_sizes[1];  // edge_eng element count
    const int N = in_sizes[2];  // atom_type element count
    const int* edge_index = (const int*)d_in[0];   // [2, E]
    const float* edge_eng = (const float*)d_in[1]; // [E, 1]
    const int* atom_type = (const int*)d_in[2];    // [N, 1]
    const float* scales = (const float*)d_in[3];   // [T, T]
    float* out = (float*)d_out;

    const int* centers = edge_index;
    const int* neighbors = edge_index + E;

    // ws layout: [tt4: C*S/2 u8 (aligned)][partials: C*B*S_CHUNK floats]
    auto al = [](size_t v) { return (v + 255) & ~(size_t)255; };
    size_t tt4_sz = al((size_t)C_CHUNKS * S_CHUNK / 2);           // 50 KB
    size_t per_b  = (size_t)C_CHUNKS * S_CHUNK * sizeof(float);   // 409.6 KB per segment

    int B = 0;
    if (N <= C_CHUNKS * S_CHUNK && ws_size > tt4_sz)
        B = (int)((ws_size - tt4_sz) / per_b);
    if (B > B_TARGET) B = B_TARGET;
    B &= ~7;   // XCD-local mapping requires B % 8 == 0

    if (B >= 8) {
        unsigned char* tt4 = (unsigned char*)d_ws;
        float* partials    = (float*)((char*)d_ws + tt4_sz);
        type_pack_kernel<<<(C_CHUNKS * S_CHUNK / 2 + 255) / 256, 256, 0, stream>>>(
            atom_type, tt4, N);
        fused_chunk_sum_kernel<<<C_CHUNKS * B, THR, 0, stream>>>(
            centers, neighbors, edge_eng, tt4, scales, partials, E, B);
        if ((N & 3) == 0)
            reduce_kernel<<<(N / 4 + 255) / 256, 256, 0, stream>>>(partials, out, B, N / 4);
        else
            reduce_scalar_kernel<<<(N + 255) / 256, 256, 0, stream>>>(partials, out, B, N);
    } else {
        hipMemsetAsync(d_out, 0, (size_t)out_size * sizeof(float), stream);
        edge_sum_atomic_kernel<<<2048, 256, 0, stream>>>(
            centers, neighbors, edge_eng, atom_type, scales, out, E);
    }
}

// Round 16
// 156.542 us; speedup vs baseline: 1.0333x; 1.0333x over previous
//
#include <hip/hip_runtime.h>

#define N_NODES 100000
#define NUM_TYPES 8
#define FACTOR 0.125f      // 1/sqrt(64)

#define S_CHUNK 25600      // nodes per chunk; bins 100 KB + full tt4 50 KB = 153.9 KB LDS
#define C_CHUNKS 4         // 4*25600 = 102400 >= 100000
#define THR 1024
#define B_TARGET 64        // grid = 4*64 = 256 blocks (1/CU)
#define NXCD 8             // blockIdx % 8 ~ XCD under round-robin dispatch

// ---------- Kernel 0: pack atom_type into nibble table (50 KB) ----------
__global__ __launch_bounds__(256) void type_pack_kernel(
    const int* __restrict__ atom_type, unsigned char* __restrict__ tt4, int N)
{
    int i = blockIdx.x * blockDim.x + threadIdx.x;   // nibble-pair index
    if (i >= C_CHUNKS * S_CHUNK / 2) return;
    int n0 = 2 * i, n1 = 2 * i + 1;
    unsigned char t0 = (n0 < N) ? (unsigned char)atom_type[n0] : 0;
    unsigned char t1 = (n1 < N) ? (unsigned char)atom_type[n1] : 0;
    tt4[i] = (unsigned char)(t0 | (t1 << 4));
}

// ---------- Kernel 1: fused chunk-sum, all-LDS lookups, x2 unrolled ----------
// FINAL STRUCTURE (r13, best measured: fused 53 us, total 156.4 us).
// Ladder: r10 1.73 cyc/edge-visit (global u8 gather) -> r12 1.39 (all-LDS
// lookups) -> r13 1.27 (x2 unroll). x4 unroll REGRESSED (r15: 58.5 us —
// conditional loads broke clause formation, VGPR stayed 52) -> ILP exhausted
// at x2; ~1.27 cyc/visit is the issue-rate floor for this op on gfx950:
// 25.6M visits x 1.27 cyc / (256 CU x 2.4 GHz) ~= 53 us.
// Mapping (r10, -4x FETCH): x=blk&7, o=blk>>3, c=o&3, b=x*(B/8)+(o>>2) keeps
// a segment's 4 chunk-blocks on one XCD -> edge lines fetched once per XCD.
__global__ __launch_bounds__(THR) void fused_chunk_sum_kernel(
    const int* __restrict__ centers,
    const int* __restrict__ neighbors,
    const float* __restrict__ eng,
    const unsigned char* __restrict__ tt4,  // [C*S/2] nibble-packed types (padded)
    const float* __restrict__ scales,
    float* __restrict__ partials,           // [C_CHUNKS][B][S_CHUNK]
    int E, int B)
{
    __shared__ __align__(16) float bins[S_CHUNK];
    __shared__ __align__(16) unsigned char s_tt4[C_CHUNKS * S_CHUNK / 2];  // 50 KB
    __shared__ float s_scales[NUM_TYPES * NUM_TYPES];

    const int x = blockIdx.x & (NXCD - 1);   // XCD id (round-robin dispatch)
    const int o = blockIdx.x >> 3;           // ordinal within XCD
    const int c = o & 3;                     // chunk
    const int b = x * (B >> 3) + (o >> 2);   // edge segment (B % 8 == 0)
    const int base = c * S_CHUNK;

    if (threadIdx.x < NUM_TYPES * NUM_TYPES)
        s_scales[threadIdx.x] = scales[threadIdx.x] * FACTOR;   // fold FACTOR

    float4* bins4 = (float4*)bins;
    for (int j = threadIdx.x; j < S_CHUNK / 4; j += THR)
        bins4[j] = make_float4(0.f, 0.f, 0.f, 0.f);
    {   // stage full nibble table: 51 200 B = 3200 uint4
        const uint4* src = (const uint4*)tt4;
        uint4* dst = (uint4*)s_tt4;
        for (int j = threadIdx.x; j < C_CHUNKS * S_CHUNK / 2 / 16; j += THR)
            dst[j] = src[j];
    }
    __syncthreads();

    const int n4 = E >> 2;

// type of global node index G from the LDS nibble table
#define TY(G)  (int)((s_tt4[(unsigned)(G) >> 1] >> (((unsigned)(G) & 1u) << 2)) & 7u)
#define BODY(CC, NN, EE) { \
        unsigned j0 = (unsigned)((CC).x - base); \
        unsigned j1 = (unsigned)((CC).y - base); \
        unsigned j2 = (unsigned)((CC).z - base); \
        unsigned j3 = (unsigned)((CC).w - base); \
        if (j0 < S_CHUNK) atomicAdd(&bins[j0], (EE).x * s_scales[TY((CC).x) * NUM_TYPES + TY((NN).x)]); \
        if (j1 < S_CHUNK) atomicAdd(&bins[j1], (EE).y * s_scales[TY((CC).y) * NUM_TYPES + TY((NN).y)]); \
        if (j2 < S_CHUNK) atomicAdd(&bins[j2], (EE).z * s_scales[TY((CC).z) * NUM_TYPES + TY((NN).z)]); \
        if (j3 < S_CHUNK) atomicAdd(&bins[j3], (EE).w * s_scales[TY((CC).w) * NUM_TYPES + TY((NN).w)]); }

    // x2-unrolled sweep: block-tile of 2*THR quads per stride; both halves
    // hoisted up front -> 8 independent edge chains in flight per thread.
    for (int i = b * (2 * THR) + (int)threadIdx.x; i < n4; i += B * (2 * THR)) {
        int4   cc0 = ((const int4*)centers)[i];
        int4   nn0 = ((const int4*)neighbors)[i];
        float4 e0  = ((const float4*)eng)[i];
        const int i1 = i + THR;
        const bool has1 = (i1 < n4);
        int4 cc1, nn1; float4 e1;
        if (has1) {
            cc1 = ((const int4*)centers)[i1];
            nn1 = ((const int4*)neighbors)[i1];
            e1  = ((const float4*)eng)[i1];
        }
        BODY(cc0, nn0, e0)
        if (has1) BODY(cc1, nn1, e1)
    }

    // tail (E % 4) — dead for E = 6,400,000; b==0 occurs once per chunk
    // (x=0, o=0..3 -> c=0..3, b=0)
    if (b == 0) {
        for (int i = (n4 << 2) + (int)threadIdx.x; i < E; i += THR) {
            int cn = centers[i];
            unsigned j = (unsigned)(cn - base);
            if (j < S_CHUNK)
                atomicAdd(&bins[j], eng[i] * s_scales[TY(cn) * NUM_TYPES + TY(neighbors[i])]);
        }
    }
#undef BODY
#undef TY

    __syncthreads();
    float4* dst4 = (float4*)(partials + ((size_t)c * B + b) * S_CHUNK);
    for (int j = threadIdx.x; j < S_CHUNK / 4; j += THR) dst4[j] = bins4[j];
}

// ---------- Kernel 2: reduce segment partials (float4) ----------
__global__ __launch_bounds__(256) void reduce_kernel(
    const float* __restrict__ partials, float* __restrict__ out, int B, int N4)
{
    int t = blockIdx.x * blockDim.x + threadIdx.x;
    if (t >= N4) return;
    int n = t * 4;
    int c = n / S_CHUNK;
    int j = n - c * S_CHUNK;
    const float4* p = (const float4*)(partials + ((size_t)c * B) * S_CHUNK + j);
    float4 s = make_float4(0.f, 0.f, 0.f, 0.f);
    for (int b = 0; b < B; ++b) {
        float4 v = p[(size_t)b * (S_CHUNK / 4)];
        s.x += v.x; s.y += v.y; s.z += v.z; s.w += v.w;
    }
    ((float4*)out)[t] = s;
}

__global__ __launch_bounds__(256) void reduce_scalar_kernel(
    const float* __restrict__ partials, float* __restrict__ out, int B, int N)
{
    int n = blockIdx.x * blockDim.x + threadIdx.x;
    if (n >= N) return;
    int c = n / S_CHUNK;
    int j = n - c * S_CHUNK;
    const float* p = partials + ((size_t)c * B) * S_CHUNK + j;
    float s = 0.0f;
    for (int b = 0; b < B; ++b) s += p[(size_t)b * S_CHUNK];
    out[n] = s;
}

// ---------- Fallback (tiny workspace only): direct atomic scatter ----------
__global__ __launch_bounds__(256) void edge_sum_atomic_kernel(
    const int* __restrict__ centers, const int* __restrict__ neighbors,
    const float* __restrict__ eng, const int* __restrict__ atom_type,
    const float* __restrict__ scales, float* __restrict__ out, int E)
{
    __shared__ float s_scales[NUM_TYPES * NUM_TYPES];
    if (threadIdx.x < NUM_TYPES * NUM_TYPES) s_scales[threadIdx.x] = scales[threadIdx.x];
    __syncthreads();
    int tid = blockIdx.x * blockDim.x + threadIdx.x;
    int stride = gridDim.x * blockDim.x;
    for (int i = tid; i < E; i += stride) {
        int cn = centers[i];
        float v = eng[i] * s_scales[atom_type[cn] * NUM_TYPES + atom_type[neighbors[i]]] * FACTOR;
        unsafeAtomicAdd(&out[cn], v);
    }
}

extern "C" void kernel_launch(void* const* d_in, const int* in_sizes, int n_in,
                              void* d_out, int out_size, void* d_ws, size_t ws_size,
                              hipStream_t stream) {
    const int E = in_sizes[1];  // edge_eng element count
    const int N = in_sizes[2];  // atom_type element count
    const int* edge_index = (const int*)d_in[0];   // [2, E]
    const float* edge_eng = (const float*)d_in[1]; // [E, 1]
    const int* atom_type = (const int*)d_in[2];    // [N, 1]
    const float* scales = (const float*)d_in[3];   // [T, T]
    float* out = (float*)d_out;

    const int* centers = edge_index;
    const int* neighbors = edge_index + E;

    // ws layout: [tt4: C*S/2 u8 (aligned)][partials: C*B*S_CHUNK floats]
    auto al = [](size_t v) { return (v + 255) & ~(size_t)255; };
    size_t tt4_sz = al((size_t)C_CHUNKS * S_CHUNK / 2);           // 50 KB
    size_t per_b  = (size_t)C_CHUNKS * S_CHUNK * sizeof(float);   // 409.6 KB per segment

    int B = 0;
    if (N <= C_CHUNKS * S_CHUNK && ws_size > tt4_sz)
        B = (int)((ws_size - tt4_sz) / per_b);
    if (B > B_TARGET) B = B_TARGET;
    B &= ~7;   // XCD-local mapping requires B % 8 == 0

    if (B >= 8) {
        unsigned char* tt4 = (unsigned char*)d_ws;
        float* partials    = (float*)((char*)d_ws + tt4_sz);
        type_pack_kernel<<<(C_CHUNKS * S_CHUNK / 2 + 255) / 256, 256, 0, stream>>>(
            atom_type, tt4, N);
        fused_chunk_sum_kernel<<<C_CHUNKS * B, THR, 0, stream>>>(
            centers, neighbors, edge_eng, tt4, scales, partials, E, B);
        if ((N & 3) == 0)
            reduce_kernel<<<(N / 4 + 255) / 256, 256, 0, stream>>>(partials, out, B, N / 4);
        else
            reduce_scalar_kernel<<<(N + 255) / 256, 256, 0, stream>>>(partials, out, B, N);
    } else {
        hipMemsetAsync(d_out, 0, (size_t)out_size * sizeof(float), stream);
        edge_sum_atomic_kernel<<<2048, 256, 0, stream>>>(
            centers, neighbors, edge_eng, atom_type, scales, out, E);
    }
}